// Round 4
// baseline (307.480 us; speedup 1.0000x reference)
//
#include <hip/hip_runtime.h>
#include <stdint.h>

#define N_NODES 50000
#define N_EDGES 800000
#define IN_F 128
#define HID_F 128
#define OUT_F 128
#define CAT_F 256

#define NBUCK 3125   // 16-node buckets (50000/16 exact)
#define BCAP 384     // per-bucket record capacity (mean 256, sigma 16, +8 sigma)
#define HB 392       // histogram blocks in K1
#define NI4 (N_EDGES / 4)  // 200000 int4 groups

typedef __bf16 bf16x8 __attribute__((ext_vector_type(8)));
typedef float f32x4 __attribute__((ext_vector_type(4)));

__device__ __forceinline__ uint32_t f2b(float f) {
  uint32_t u = __float_as_uint(f);
  return (u + 0x7fffu + ((u >> 16) & 1u)) >> 16;  // RNE
}

// ---- K1: fused  [0,HB): per-bucket histogram via direct global atomics into
// gcur (pre-zeroed by hipMemsetAsync) | [HB,..): h/Qw/Ww -> bf16 convert.
// R4: replaces the per-partition G-matrix counting sort (G/Gs column-strided
// access was ~16x fetch-amplified, ~50 MB each way) with 800k direct atomics
// over 3125 counters (~256/counter, negligible contention).
__global__ void __launch_bounds__(256) prep_kernel(
    const int* __restrict__ dst, int* __restrict__ gcur, const float* __restrict__ h,
    const float* __restrict__ Qw, const float* __restrict__ Ww, uint16_t* __restrict__ hB,
    uint16_t* __restrict__ QwB, uint16_t* __restrict__ WwB) {
  if (blockIdx.x < HB) {
    int tid = blockIdx.x * 256 + threadIdx.x;
    for (int i4 = tid; i4 < NI4; i4 += HB * 256) {
      int4 d4 = ((const int4*)dst)[i4];
      atomicAdd(&gcur[d4.x >> 4], 1);
      atomicAdd(&gcur[d4.y >> 4], 1);
      atomicAdd(&gcur[d4.z >> 4], 1);
      atomicAdd(&gcur[d4.w >> 4], 1);
    }
  } else {
    const int TOT4 = (N_NODES * IN_F + HID_F * IN_F + OUT_F * CAT_F) / 4;  // 1612288
    int i4 = (blockIdx.x - HB) * 256 + threadIdx.x;
    if (i4 >= TOT4) return;
    int base = i4 * 4;
    const float* src;
    uint16_t* dstp;
    int off;
    if (base < N_NODES * IN_F) {
      src = h; dstp = hB; off = base;
    } else if (base < N_NODES * IN_F + HID_F * IN_F) {
      src = Qw; dstp = QwB; off = base - N_NODES * IN_F;
    } else {
      src = Ww; dstp = WwB; off = base - N_NODES * IN_F - HID_F * IN_F;
    }
    float4 v = *(const float4*)(src + off);
    ushort4 o;
    o.x = (uint16_t)f2b(v.x); o.y = (uint16_t)f2b(v.y);
    o.z = (uint16_t)f2b(v.z); o.w = (uint16_t)f2b(v.w);
    *(ushort4*)(dstp + off) = o;
  }
}

// ---- K2: single-wave scan of gcur counts -> Bbase[NBUCK+1]; rewrite gcur as
// the scatter cursor (gcur[k] = Bbase[k]). Each thread reads/writes only its
// own 49-element range, so in-place is race-free.
__global__ void scan_kernel(int* __restrict__ gcur, int* __restrict__ Bbase) {
  int lane = threadIdx.x;  // 64 threads, 49 elems each (3136 >= 3126)
  int c[49], loc[49];
  int s = 0;
#pragma unroll
  for (int j = 0; j < 49; ++j) {
    int i = lane * 49 + j;
    c[j] = (i < NBUCK) ? gcur[i] : 0;
    loc[j] = s;
    s += c[j];
  }
  int inc = s;
#pragma unroll
  for (int d = 1; d < 64; d <<= 1) {
    int x = __shfl_up(inc, d, 64);
    if (lane >= d) inc += x;
  }
  int exc = inc - s;
#pragma unroll
  for (int j = 0; j < 49; ++j) {
    int i = lane * 49 + j;
    int v = exc + loc[j];
    if (i <= NBUCK) Bbase[i] = v;
    if (i < NBUCK) gcur[i] = v;
  }
}

// ---- K3: scatter records via global atomic cursors. One thread per int4
// group of 4 edges; rec[p] = {src | local_dst<<20, weight}.
__global__ void __launch_bounds__(256) scatter_kernel(
    const int* __restrict__ dst, const int* __restrict__ src, const float* __restrict__ ppr,
    int* __restrict__ gcur, int2* __restrict__ rec) {
  int i4 = blockIdx.x * 256 + threadIdx.x;
  if (i4 >= NI4) return;
  int4 d4 = ((const int4*)dst)[i4];
  int4 s4 = ((const int4*)src)[i4];
  float4 w4 = ((const float4*)ppr)[i4];
  int p;
  p = atomicAdd(&gcur[d4.x >> 4], 1);
  rec[p] = make_int2(s4.x | ((d4.x & 15) << 20), __float_as_int(w4.x));
  p = atomicAdd(&gcur[d4.y >> 4], 1);
  rec[p] = make_int2(s4.y | ((d4.y & 15) << 20), __float_as_int(w4.y));
  p = atomicAdd(&gcur[d4.z >> 4], 1);
  rec[p] = make_int2(s4.z | ((d4.z & 15) << 20), __float_as_int(w4.z));
  p = atomicAdd(&gcur[d4.w >> 4], 1);
  rec[p] = make_int2(s4.w | ((d4.w & 15) << 20), __float_as_int(w4.w));
}

// ---- K4: fused aggregation + Q + GEMM2. Block g (256 thr, 4 waves) owns 16
// nodes. R4 algebra: Q is linear, so aggregate RAW h (gather hB rows) and
// apply Q afterwards as a tiny per-block GEMM:
//   h_agg = safediv(sum w*h[src], sum w) @ Qw^T + Qb   (Qb gated by ws!=0)
// This deletes gemm1 and the hqB buffer. P4.5 (Q) and P5 (gemm2) are split
// across all 4 waves; the L2 norm is cross-wave-reduced via LDS.
__global__ void __launch_bounds__(256) agg_gemm2_kernel(
    const int2* __restrict__ rec, const int* __restrict__ Bbase,
    const uint16_t* __restrict__ hB, const uint16_t* __restrict__ QwB,
    const float* __restrict__ Qb, const uint16_t* __restrict__ WwB,
    const float* __restrict__ Wb, float* __restrict__ out) {
  __shared__ int2 srec[BCAP];     // 3.0 KB
  __shared__ uint4 hagg[16][17];  // raw aggregated h, bf16 (pad breaks conflicts)
  __shared__ uint4 hq2[16][17];   // Q-transformed agg, bf16
  __shared__ int hist[16];
  __shared__ int noff[17];
  __shared__ int cur[16];
  __shared__ float wsum[16];
  __shared__ float ssp[4][16];    // per-wave partial squared-norms
  int g = blockIdx.x;
  int t = threadIdx.x;
  if (t < 16) hist[t] = 0;
  __syncthreads();

  int rbeg = Bbase[g];
  int len = Bbase[g + 1] - rbeg;
  len = (len < BCAP) ? len : BCAP;

  // P1: load to registers + histogram (2*256 >= BCAP)
  int2 rc[2];
#pragma unroll
  for (int k = 0; k < 2; ++k) {
    int i = t + k * 256;
    if (i < len) {
      rc[k] = rec[rbeg + i];
      atomicAdd(&hist[rc[k].x >> 20], 1);
    }
  }
  __syncthreads();

  // P2: exclusive scan of 16 counters (lanes 0..15 of wave 0)
  if (t < 16) {
    int v = hist[t];
    int inc = v;
#pragma unroll
    for (int d = 1; d < 16; d <<= 1) {
      int x = __shfl_up(inc, d, 64);
      if (t >= d) inc += x;
    }
    noff[t] = inc - v;
    cur[t] = inc - v;
    if (t == 15) noff[16] = inc;
  }
  __syncthreads();

  // P3: scatter registers -> node-sorted LDS
#pragma unroll
  for (int k = 0; k < 2; ++k) {
    int i = t + k * 256;
    if (i < len) {
      int p = atomicAdd(&cur[rc[k].x >> 20], 1);
      srec[p] = rc[k];
    }
  }
  __syncthreads();

  // P4: sub-as-node aggregation of RAW h with 2-deep ping-pong prefetch.
  // 16 subs of 16 lanes; each sub owns 1 node (3125*16 = 50000 exactly).
  {
    int gs = t >> 4, c = t & 15;
    const uint4* hb4 = (const uint4*)hB;
    int nl = gs;
    int nbeg = noff[nl], nend = noff[nl + 1];
    int last = nend - 1;
    float a[8];
#pragma unroll
    for (int j = 0; j < 8; ++j) a[j] = 0.f;
    float ws = 0.f;

    int2 rrA[4], rrB[4];
    uint4 uA[4], uB[4];

#define LOADB(E0, RR, UU)                                         \
  {                                                               \
    _Pragma("unroll") for (int j = 0; j < 4; ++j) {               \
      int i = (E0) + j;                                           \
      RR[j] = srec[(i < last) ? i : last];                        \
    }                                                             \
    _Pragma("unroll") for (int j = 0; j < 4; ++j)                 \
        UU[j] = hb4[(size_t)(RR[j].x & 0xFFFFF) * 16 + c];        \
  }

#define CONSB(E0, RR, UU)                                           \
  {                                                                 \
    _Pragma("unroll") for (int j = 0; j < 4; ++j) {                 \
      float w = ((E0) + j < nend) ? __int_as_float(RR[j].y) : 0.f;  \
      ws += w;                                                      \
      uint32_t x;                                                   \
      x = UU[j].x;                                                  \
      a[0] += w * __uint_as_float(x << 16);                         \
      a[1] += w * __uint_as_float(x & 0xffff0000u);                 \
      x = UU[j].y;                                                  \
      a[2] += w * __uint_as_float(x << 16);                         \
      a[3] += w * __uint_as_float(x & 0xffff0000u);                 \
      x = UU[j].z;                                                  \
      a[4] += w * __uint_as_float(x << 16);                         \
      a[5] += w * __uint_as_float(x & 0xffff0000u);                 \
      x = UU[j].w;                                                  \
      a[6] += w * __uint_as_float(x << 16);                         \
      a[7] += w * __uint_as_float(x & 0xffff0000u);                 \
    }                                                               \
  }

    int e = nbeg;
    if (e < nend) {
      LOADB(e, rrA, uA);
      while (true) {
        int eB = e + 4;
        if (eB < nend) {
          LOADB(eB, rrB, uB);   // B in flight while A consumed
          CONSB(e, rrA, uA);
          int eA = eB + 4;
          if (eA < nend) {
            LOADB(eA, rrA, uA); // A in flight while B consumed
            CONSB(eB, rrB, uB);
            e = eA;
          } else {
            CONSB(eB, rrB, uB);
            break;
          }
        } else {
          CONSB(e, rrA, uA);
          break;
        }
      }
    }
#undef LOADB
#undef CONSB

    float dnm = (ws == 0.f) ? 1.f : ws;  // safediv
    float inv = 1.f / dnm;
    uint4 o;
    o.x = f2b(a[0] * inv) | (f2b(a[1] * inv) << 16);
    o.y = f2b(a[2] * inv) | (f2b(a[3] * inv) << 16);
    o.z = f2b(a[4] * inv) | (f2b(a[5] * inv) << 16);
    o.w = f2b(a[6] * inv) | (f2b(a[7] * inv) << 16);
    hagg[nl][c] = o;
    if (c == 0) wsum[nl] = ws;
  }
  __syncthreads();

  int lane = t & 63, wv = t >> 6;
  int r = lane & 15, qd = lane >> 4;

  // P4.5: hq2 = hagg @ Qw^T + Qb (Qb gated by ws!=0, matching safediv on an
  // empty node where the reference yields 0 not Qb). 8 col-tiles over 4 waves.
#pragma unroll
  for (int tq = 0; tq < 2; ++tq) {
    int tt = wv * 2 + tq;
    f32x4 acc = (f32x4){0.f, 0.f, 0.f, 0.f};
#pragma unroll
    for (int kt = 0; kt < 4; ++kt) {
      bf16x8 av = *(const bf16x8*)&hagg[r][kt * 4 + qd];
      bf16x8 b = *(const bf16x8*)(QwB + (tt * 16 + r) * IN_F + kt * 32 + qd * 8);
      acc = __builtin_amdgcn_mfma_f32_16x16x32_bf16(av, b, acc, 0, 0, 0);
    }
    float qb = Qb[tt * 16 + r];
#pragma unroll
    for (int rr2 = 0; rr2 < 4; ++rr2) {
      int row = qd * 4 + rr2;
      float flag = (wsum[row] != 0.f) ? 1.f : 0.f;
      ((uint16_t*)&hq2[row][0])[tt * 16 + r] = (uint16_t)f2b(acc[rr2] + qb * flag);
    }
  }
  __syncthreads();

  // P5: gemm2 out = leaky([hB | hq2] @ Ww^T + Wb), L2-normalized per row.
  // 8 col-tiles over 4 waves; norm cross-wave-reduced via ssp.
  int row0 = g * 16;
  f32x4 acc2[2];
  acc2[0] = (f32x4){0.f, 0.f, 0.f, 0.f};
  acc2[1] = (f32x4){0.f, 0.f, 0.f, 0.f};
  const uint16_t* aRow = hB + (size_t)(row0 + r) * IN_F + qd * 8;
#pragma unroll
  for (int kt = 0; kt < 8; ++kt) {
    bf16x8 av;
    if (kt < 4) {
      av = *(const bf16x8*)(aRow + kt * 32);
    } else {
      av = *(const bf16x8*)&hq2[r][(kt - 4) * 4 + qd];
    }
#pragma unroll
    for (int tq = 0; tq < 2; ++tq) {
      int tt = wv * 2 + tq;
      bf16x8 b = *(const bf16x8*)(WwB + (tt * 16 + r) * CAT_F + kt * 32 + qd * 8);
      acc2[tq] = __builtin_amdgcn_mfma_f32_16x16x32_bf16(av, b, acc2[tq], 0, 0, 0);
    }
  }
  float lv[2][4];
  float ss[4] = {0.f, 0.f, 0.f, 0.f};
#pragma unroll
  for (int tq = 0; tq < 2; ++tq) {
    int tt = wv * 2 + tq;
    float wb = Wb[tt * 16 + r];
#pragma unroll
    for (int rr2 = 0; rr2 < 4; ++rr2) {
      float v = acc2[tq][rr2] + wb;
      v = (v >= 0.f) ? v : 0.01f * v;
      lv[tq][rr2] = v;
      ss[rr2] += v * v;
    }
  }
#pragma unroll
  for (int rr2 = 0; rr2 < 4; ++rr2) {
    float s = ss[rr2];
    s += __shfl_xor(s, 1);
    s += __shfl_xor(s, 2);
    s += __shfl_xor(s, 4);
    s += __shfl_xor(s, 8);
    ss[rr2] = s;  // sum over this wave's 32 cols, all lanes hold it
  }
  if (r == 0) {
#pragma unroll
    for (int rr2 = 0; rr2 < 4; ++rr2) ssp[wv][qd * 4 + rr2] = ss[rr2];
  }
  __syncthreads();
#pragma unroll
  for (int rr2 = 0; rr2 < 4; ++rr2) {
    int row = qd * 4 + rr2;
    float tot = ssp[0][row] + ssp[1][row] + ssp[2][row] + ssp[3][row];
    float nr = sqrtf(tot);
    float inv = (nr == 0.f) ? 1.f : (1.f / nr);
    float* orow = out + (size_t)(row0 + row) * OUT_F;
#pragma unroll
    for (int tq = 0; tq < 2; ++tq) {
      int tt = wv * 2 + tq;
      orow[tt * 16 + r] = lv[tq][rr2] * inv;
    }
  }
}

extern "C" void kernel_launch(void* const* d_in, const int* in_sizes, int n_in,
                              void* d_out, int out_size, void* d_ws, size_t ws_size,
                              hipStream_t stream) {
  const float* h = (const float*)d_in[0];
  const float* ppr = (const float*)d_in[1];
  const float* Qw = (const float*)d_in[2];
  const float* Qb = (const float*)d_in[3];
  const float* Ww = (const float*)d_in[4];
  const float* Wb = (const float*)d_in[5];
  const int* src = (const int*)d_in[6];
  const int* dst = (const int*)d_in[7];
  float* out = (float*)d_out;

  char* ws = (char*)d_ws;
  size_t o = 0;
  auto alloc = [&](size_t bytes) {
    void* p = ws + o;
    o = (o + bytes + 255) & ~(size_t)255;
    return p;
  };
  uint16_t* hB = (uint16_t*)alloc((size_t)N_NODES * IN_F * 2);  // 12.8 MB
  uint16_t* QwB = (uint16_t*)alloc((size_t)HID_F * IN_F * 2);
  uint16_t* WwB = (uint16_t*)alloc((size_t)OUT_F * CAT_F * 2);
  int* gcur = (int*)alloc((size_t)NBUCK * 4);        // counts, then cursors
  int* Bbase = (int*)alloc((size_t)(NBUCK + 1) * 4);
  int2* rec = (int2*)alloc((size_t)N_EDGES * 8);     // 6.4 MB
  // total ~19.3 MB

  const int CONV_BLOCKS = ((N_NODES * IN_F + HID_F * IN_F + OUT_F * CAT_F) / 4 + 255) / 256;
  hipMemsetAsync(gcur, 0, (size_t)NBUCK * 4, stream);
  prep_kernel<<<HB + CONV_BLOCKS, 256, 0, stream>>>(dst, gcur, h, Qw, Ww, hB, QwB, WwB);
  scan_kernel<<<1, 64, 0, stream>>>(gcur, Bbase);
  scatter_kernel<<<(NI4 + 255) / 256, 256, 0, stream>>>(dst, src, ppr, gcur, rec);
  agg_gemm2_kernel<<<NBUCK, 256, 0, stream>>>(rec, Bbase, hB, QwB, Qb, WwB, Wb, out);
}

// Round 5
// 195.280 us; speedup vs baseline: 1.5746x; 1.5746x over previous
//
#include <hip/hip_runtime.h>
#include <stdint.h>

#define N_NODES 50000
#define N_EDGES 800000
#define IN_F 128
#define HID_F 128
#define OUT_F 128
#define CAT_F 256

#define NB 256       // edge partition blocks
#define CHUNK 3136   // edges per partition (int4-aligned; 256*3136 >= 800000)
#define NBUCK 3125   // 16-node buckets (50000/16 exact)
#define BCAP 384     // per-bucket record capacity (mean 256, sigma 16, +8 sigma)

typedef __bf16 bf16x8 __attribute__((ext_vector_type(8)));
typedef float f32x4 __attribute__((ext_vector_type(4)));

__device__ __forceinline__ uint32_t f2b(float f) {
  uint32_t u = __float_as_uint(f);
  return (u + 0x7fffu + ((u >> 16) & 1u)) >> 16;  // RNE
}

// ---- K1: fused  [0,NB): per-partition LDS histogram -> G row (BLOCK-major,
// coalesced write) | [NB,..): h/Qw/Ww -> bf16 convert.
// R5: G[b*NBUCK+k] (block-major). R3 stored it bucket-major, making this write
// a 12.5KB-stride column (~51 MB line-amplified); now it's a contiguous 12.5KB
// stream per block.
__global__ void __launch_bounds__(256) prep_hist_kernel(
    const int* __restrict__ dst, int* __restrict__ G, const float* __restrict__ h,
    const float* __restrict__ Qw, const float* __restrict__ Ww, uint16_t* __restrict__ hB,
    uint16_t* __restrict__ QwB, uint16_t* __restrict__ WwB) {
  if (blockIdx.x < NB) {
    __shared__ int hist[NBUCK];  // 12.5 KB
    for (int k = threadIdx.x; k < NBUCK; k += 256) hist[k] = 0;
    __syncthreads();
    int b = blockIdx.x;
    int base = b * CHUNK;
    int end = (base + CHUNK < N_EDGES) ? (base + CHUNK) : N_EDGES;
    for (int i4 = base / 4 + threadIdx.x; i4 * 4 < end; i4 += 256) {
      int4 d4 = ((const int4*)dst)[i4];  // CHUNK,N_EDGES divisible by 4
      atomicAdd(&hist[d4.x >> 4], 1);
      atomicAdd(&hist[d4.y >> 4], 1);
      atomicAdd(&hist[d4.z >> 4], 1);
      atomicAdd(&hist[d4.w >> 4], 1);
    }
    __syncthreads();
    for (int k = threadIdx.x; k < NBUCK; k += 256) G[(size_t)b * NBUCK + k] = hist[k];
  } else {
    const int TOT4 = (N_NODES * IN_F + HID_F * IN_F + OUT_F * CAT_F) / 4;  // 1612288
    int i4 = (blockIdx.x - NB) * 256 + threadIdx.x;
    if (i4 >= TOT4) return;
    int base = i4 * 4;
    const float* src;
    uint16_t* dstp;
    int off;
    if (base < N_NODES * IN_F) {
      src = h; dstp = hB; off = base;
    } else if (base < N_NODES * IN_F + HID_F * IN_F) {
      src = Qw; dstp = QwB; off = base - N_NODES * IN_F;
    } else {
      src = Ww; dstp = WwB; off = base - N_NODES * IN_F - HID_F * IN_F;
    }
    float4 v = *(const float4*)(src + off);
    ushort4 o;
    o.x = (uint16_t)f2b(v.x); o.y = (uint16_t)f2b(v.y);
    o.z = (uint16_t)f2b(v.z); o.w = (uint16_t)f2b(v.w);
    *(ushort4*)(dstp + off) = o;
  }
}

// ---- K2a: per-bucket exclusive scan over its NB=256 partition counts,
// IN-PLACE in block-major G (each lane rewrites only its own cells). The
// strided accesses hit L2 (G = 3.2MB, resident; adjacent waves touch adjacent
// words of the same lines). One wave per bucket; lane l covers b in [4l,4l+4).
__global__ void __launch_bounds__(256) colscan_kernel(int* __restrict__ G,
                                                      int* __restrict__ Btot) {
  int w = (blockIdx.x * 256 + (int)threadIdx.x) >> 6;  // bucket id
  if (w >= NBUCK) return;
  int lane = threadIdx.x & 63;
  int v0 = G[(size_t)(4 * lane + 0) * NBUCK + w];
  int v1 = G[(size_t)(4 * lane + 1) * NBUCK + w];
  int v2 = G[(size_t)(4 * lane + 2) * NBUCK + w];
  int v3 = G[(size_t)(4 * lane + 3) * NBUCK + w];
  int s = v0 + v1 + v2 + v3;
  int inc = s;
#pragma unroll
  for (int d = 1; d < 64; d <<= 1) {
    int x = __shfl_up(inc, d, 64);
    if (lane >= d) inc += x;
  }
  int exc = inc - s;
  G[(size_t)(4 * lane + 0) * NBUCK + w] = exc;
  G[(size_t)(4 * lane + 1) * NBUCK + w] = exc + v0;
  G[(size_t)(4 * lane + 2) * NBUCK + w] = exc + v0 + v1;
  G[(size_t)(4 * lane + 3) * NBUCK + w] = exc + v0 + v1 + v2;
  if (lane == 63) Btot[w] = inc;
}

// ---- K2b: single-wave exclusive scan of NBUCK bucket totals -> Bbase[NBUCK+1]
__global__ void base_scan_kernel(const int* __restrict__ Btot, int* __restrict__ Bbase) {
  int lane = threadIdx.x;  // 64 threads, 49 elems each (3136 >= 3126)
  int c[49], loc[49];
  int s = 0;
#pragma unroll
  for (int j = 0; j < 49; ++j) {
    int i = lane * 49 + j;
    c[j] = (i < NBUCK) ? Btot[i] : 0;
    loc[j] = s;
    s += c[j];
  }
  int inc = s;
#pragma unroll
  for (int d = 1; d < 64; d <<= 1) {
    int x = __shfl_up(inc, d, 64);
    if (lane >= d) inc += x;
  }
  int exc = inc - s;
#pragma unroll
  for (int j = 0; j < 49; ++j) {
    int i = lane * 49 + j;
    if (i <= NBUCK) Bbase[i] = exc + loc[j];
  }
}

// ---- K3: scatter via per-partition LDS cursors (fire-and-forget-free; the
// position atomic is in LDS, not contended L2 like R4's 75us version).
// Cursor init reads Bbase + this block's G row -- both contiguous/coalesced.
__global__ void __launch_bounds__(256) scatter_kernel(
    const int* __restrict__ dst, const int* __restrict__ src, const float* __restrict__ ppr,
    const int* __restrict__ G, const int* __restrict__ Bbase, int2* __restrict__ rec) {
  __shared__ int cursor[NBUCK];  // 12.5 KB
  int b = blockIdx.x;
  for (int k = threadIdx.x; k < NBUCK; k += 256)
    cursor[k] = Bbase[k] + G[(size_t)b * NBUCK + k];
  __syncthreads();
  int base = b * CHUNK;
  int end = (base + CHUNK < N_EDGES) ? (base + CHUNK) : N_EDGES;
  for (int i4 = base / 4 + threadIdx.x; i4 * 4 < end; i4 += 256) {
    int4 d4 = ((const int4*)dst)[i4];
    int4 s4 = ((const int4*)src)[i4];
    float4 w4 = ((const float4*)ppr)[i4];
    int p;
    p = atomicAdd(&cursor[d4.x >> 4], 1);
    rec[p] = make_int2(s4.x | ((d4.x & 15) << 20), __float_as_int(w4.x));
    p = atomicAdd(&cursor[d4.y >> 4], 1);
    rec[p] = make_int2(s4.y | ((d4.y & 15) << 20), __float_as_int(w4.y));
    p = atomicAdd(&cursor[d4.z >> 4], 1);
    rec[p] = make_int2(s4.z | ((d4.z & 15) << 20), __float_as_int(w4.z));
    p = atomicAdd(&cursor[d4.w >> 4], 1);
    rec[p] = make_int2(s4.w | ((d4.w & 15) << 20), __float_as_int(w4.w));
  }
}

// ---- K4: fused aggregation + Q + GEMM2 (verbatim from R4, which passed).
// Block g (256 thr, 4 waves) owns 16 nodes. Q is linear, so aggregate RAW h
// and apply Q afterwards as a tiny per-block GEMM:
//   h_agg = safediv(sum w*h[src], sum w) @ Qw^T + Qb   (Qb gated by ws!=0)
__global__ void __launch_bounds__(256) agg_gemm2_kernel(
    const int2* __restrict__ rec, const int* __restrict__ Bbase,
    const uint16_t* __restrict__ hB, const uint16_t* __restrict__ QwB,
    const float* __restrict__ Qb, const uint16_t* __restrict__ WwB,
    const float* __restrict__ Wb, float* __restrict__ out) {
  __shared__ int2 srec[BCAP];     // 3.0 KB
  __shared__ uint4 hagg[16][17];  // raw aggregated h, bf16 (pad breaks conflicts)
  __shared__ uint4 hq2[16][17];   // Q-transformed agg, bf16
  __shared__ int hist[16];
  __shared__ int noff[17];
  __shared__ int cur[16];
  __shared__ float wsum[16];
  __shared__ float ssp[4][16];    // per-wave partial squared-norms
  int g = blockIdx.x;
  int t = threadIdx.x;
  if (t < 16) hist[t] = 0;
  __syncthreads();

  int rbeg = Bbase[g];
  int len = Bbase[g + 1] - rbeg;
  len = (len < BCAP) ? len : BCAP;

  // P1: load to registers + histogram (2*256 >= BCAP)
  int2 rc[2];
#pragma unroll
  for (int k = 0; k < 2; ++k) {
    int i = t + k * 256;
    if (i < len) {
      rc[k] = rec[rbeg + i];
      atomicAdd(&hist[rc[k].x >> 20], 1);
    }
  }
  __syncthreads();

  // P2: exclusive scan of 16 counters (lanes 0..15 of wave 0)
  if (t < 16) {
    int v = hist[t];
    int inc = v;
#pragma unroll
    for (int d = 1; d < 16; d <<= 1) {
      int x = __shfl_up(inc, d, 64);
      if (t >= d) inc += x;
    }
    noff[t] = inc - v;
    cur[t] = inc - v;
    if (t == 15) noff[16] = inc;
  }
  __syncthreads();

  // P3: scatter registers -> node-sorted LDS
#pragma unroll
  for (int k = 0; k < 2; ++k) {
    int i = t + k * 256;
    if (i < len) {
      int p = atomicAdd(&cur[rc[k].x >> 20], 1);
      srec[p] = rc[k];
    }
  }
  __syncthreads();

  // P4: sub-as-node aggregation of RAW h with 2-deep ping-pong prefetch.
  // 16 subs of 16 lanes; each sub owns 1 node (3125*16 = 50000 exactly).
  {
    int gs = t >> 4, c = t & 15;
    const uint4* hb4 = (const uint4*)hB;
    int nl = gs;
    int nbeg = noff[nl], nend = noff[nl + 1];
    int last = nend - 1;
    float a[8];
#pragma unroll
    for (int j = 0; j < 8; ++j) a[j] = 0.f;
    float ws = 0.f;

    int2 rrA[4], rrB[4];
    uint4 uA[4], uB[4];

#define LOADB(E0, RR, UU)                                         \
  {                                                               \
    _Pragma("unroll") for (int j = 0; j < 4; ++j) {               \
      int i = (E0) + j;                                           \
      RR[j] = srec[(i < last) ? i : last];                        \
    }                                                             \
    _Pragma("unroll") for (int j = 0; j < 4; ++j)                 \
        UU[j] = hb4[(size_t)(RR[j].x & 0xFFFFF) * 16 + c];        \
  }

#define CONSB(E0, RR, UU)                                           \
  {                                                                 \
    _Pragma("unroll") for (int j = 0; j < 4; ++j) {                 \
      float w = ((E0) + j < nend) ? __int_as_float(RR[j].y) : 0.f;  \
      ws += w;                                                      \
      uint32_t x;                                                   \
      x = UU[j].x;                                                  \
      a[0] += w * __uint_as_float(x << 16);                         \
      a[1] += w * __uint_as_float(x & 0xffff0000u);                 \
      x = UU[j].y;                                                  \
      a[2] += w * __uint_as_float(x << 16);                         \
      a[3] += w * __uint_as_float(x & 0xffff0000u);                 \
      x = UU[j].z;                                                  \
      a[4] += w * __uint_as_float(x << 16);                         \
      a[5] += w * __uint_as_float(x & 0xffff0000u);                 \
      x = UU[j].w;                                                  \
      a[6] += w * __uint_as_float(x << 16);                         \
      a[7] += w * __uint_as_float(x & 0xffff0000u);                 \
    }                                                               \
  }

    int e = nbeg;
    if (e < nend) {
      LOADB(e, rrA, uA);
      while (true) {
        int eB = e + 4;
        if (eB < nend) {
          LOADB(eB, rrB, uB);   // B in flight while A consumed
          CONSB(e, rrA, uA);
          int eA = eB + 4;
          if (eA < nend) {
            LOADB(eA, rrA, uA); // A in flight while B consumed
            CONSB(eB, rrB, uB);
            e = eA;
          } else {
            CONSB(eB, rrB, uB);
            break;
          }
        } else {
          CONSB(e, rrA, uA);
          break;
        }
      }
    }
#undef LOADB
#undef CONSB

    float dnm = (ws == 0.f) ? 1.f : ws;  // safediv
    float inv = 1.f / dnm;
    uint4 o;
    o.x = f2b(a[0] * inv) | (f2b(a[1] * inv) << 16);
    o.y = f2b(a[2] * inv) | (f2b(a[3] * inv) << 16);
    o.z = f2b(a[4] * inv) | (f2b(a[5] * inv) << 16);
    o.w = f2b(a[6] * inv) | (f2b(a[7] * inv) << 16);
    hagg[nl][c] = o;
    if (c == 0) wsum[nl] = ws;
  }
  __syncthreads();

  int lane = t & 63, wv = t >> 6;
  int r = lane & 15, qd = lane >> 4;

  // P4.5: hq2 = hagg @ Qw^T + Qb (Qb gated by ws!=0, matching safediv on an
  // empty node where the reference yields 0 not Qb). 8 col-tiles over 4 waves.
#pragma unroll
  for (int tq = 0; tq < 2; ++tq) {
    int tt = wv * 2 + tq;
    f32x4 acc = (f32x4){0.f, 0.f, 0.f, 0.f};
#pragma unroll
    for (int kt = 0; kt < 4; ++kt) {
      bf16x8 av = *(const bf16x8*)&hagg[r][kt * 4 + qd];
      bf16x8 b = *(const bf16x8*)(QwB + (tt * 16 + r) * IN_F + kt * 32 + qd * 8);
      acc = __builtin_amdgcn_mfma_f32_16x16x32_bf16(av, b, acc, 0, 0, 0);
    }
    float qb = Qb[tt * 16 + r];
#pragma unroll
    for (int rr2 = 0; rr2 < 4; ++rr2) {
      int row = qd * 4 + rr2;
      float flag = (wsum[row] != 0.f) ? 1.f : 0.f;
      ((uint16_t*)&hq2[row][0])[tt * 16 + r] = (uint16_t)f2b(acc[rr2] + qb * flag);
    }
  }
  __syncthreads();

  // P5: gemm2 out = leaky([hB | hq2] @ Ww^T + Wb), L2-normalized per row.
  // 8 col-tiles over 4 waves; norm cross-wave-reduced via ssp.
  int row0 = g * 16;
  f32x4 acc2[2];
  acc2[0] = (f32x4){0.f, 0.f, 0.f, 0.f};
  acc2[1] = (f32x4){0.f, 0.f, 0.f, 0.f};
  const uint16_t* aRow = hB + (size_t)(row0 + r) * IN_F + qd * 8;
#pragma unroll
  for (int kt = 0; kt < 8; ++kt) {
    bf16x8 av;
    if (kt < 4) {
      av = *(const bf16x8*)(aRow + kt * 32);
    } else {
      av = *(const bf16x8*)&hq2[r][(kt - 4) * 4 + qd];
    }
#pragma unroll
    for (int tq = 0; tq < 2; ++tq) {
      int tt = wv * 2 + tq;
      bf16x8 b = *(const bf16x8*)(WwB + (tt * 16 + r) * CAT_F + kt * 32 + qd * 8);
      acc2[tq] = __builtin_amdgcn_mfma_f32_16x16x32_bf16(av, b, acc2[tq], 0, 0, 0);
    }
  }
  float lv[2][4];
  float ss[4] = {0.f, 0.f, 0.f, 0.f};
#pragma unroll
  for (int tq = 0; tq < 2; ++tq) {
    int tt = wv * 2 + tq;
    float wb = Wb[tt * 16 + r];
#pragma unroll
    for (int rr2 = 0; rr2 < 4; ++rr2) {
      float v = acc2[tq][rr2] + wb;
      v = (v >= 0.f) ? v : 0.01f * v;
      lv[tq][rr2] = v;
      ss[rr2] += v * v;
    }
  }
#pragma unroll
  for (int rr2 = 0; rr2 < 4; ++rr2) {
    float s = ss[rr2];
    s += __shfl_xor(s, 1);
    s += __shfl_xor(s, 2);
    s += __shfl_xor(s, 4);
    s += __shfl_xor(s, 8);
    ss[rr2] = s;  // sum over this wave's 32 cols, all lanes hold it
  }
  if (r == 0) {
#pragma unroll
    for (int rr2 = 0; rr2 < 4; ++rr2) ssp[wv][qd * 4 + rr2] = ss[rr2];
  }
  __syncthreads();
#pragma unroll
  for (int rr2 = 0; rr2 < 4; ++rr2) {
    int row = qd * 4 + rr2;
    float tot = ssp[0][row] + ssp[1][row] + ssp[2][row] + ssp[3][row];
    float nr = sqrtf(tot);
    float inv = (nr == 0.f) ? 1.f : (1.f / nr);
    float* orow = out + (size_t)(row0 + row) * OUT_F;
#pragma unroll
    for (int tq = 0; tq < 2; ++tq) {
      int tt = wv * 2 + tq;
      orow[tt * 16 + r] = lv[tq][rr2] * inv;
    }
  }
}

extern "C" void kernel_launch(void* const* d_in, const int* in_sizes, int n_in,
                              void* d_out, int out_size, void* d_ws, size_t ws_size,
                              hipStream_t stream) {
  const float* h = (const float*)d_in[0];
  const float* ppr = (const float*)d_in[1];
  const float* Qw = (const float*)d_in[2];
  const float* Qb = (const float*)d_in[3];
  const float* Ww = (const float*)d_in[4];
  const float* Wb = (const float*)d_in[5];
  const int* src = (const int*)d_in[6];
  const int* dst = (const int*)d_in[7];
  float* out = (float*)d_out;

  char* ws = (char*)d_ws;
  size_t o = 0;
  auto alloc = [&](size_t bytes) {
    void* p = ws + o;
    o = (o + bytes + 255) & ~(size_t)255;
    return p;
  };
  uint16_t* hB = (uint16_t*)alloc((size_t)N_NODES * IN_F * 2);  // 12.8 MB
  uint16_t* QwB = (uint16_t*)alloc((size_t)HID_F * IN_F * 2);
  uint16_t* WwB = (uint16_t*)alloc((size_t)OUT_F * CAT_F * 2);
  int* G = (int*)alloc((size_t)NB * NBUCK * 4);      // 3.2 MB, block-major
  int* Btot = (int*)alloc((size_t)NBUCK * 4);
  int* Bbase = (int*)alloc((size_t)(NBUCK + 1) * 4);
  int2* rec = (int2*)alloc((size_t)N_EDGES * 8);     // 6.4 MB
  // total ~22.5 MB; no memset needed (all buffers fully written each call)

  const int CONV_BLOCKS = ((N_NODES * IN_F + HID_F * IN_F + OUT_F * CAT_F) / 4 + 255) / 256;
  prep_hist_kernel<<<NB + CONV_BLOCKS, 256, 0, stream>>>(dst, G, h, Qw, Ww, hB, QwB, WwB);
  colscan_kernel<<<(NBUCK + 3) / 4, 256, 0, stream>>>(G, Btot);
  base_scan_kernel<<<1, 64, 0, stream>>>(Btot, Bbase);
  scatter_kernel<<<NB, 256, 0, stream>>>(dst, src, ppr, G, Bbase, rec);
  agg_gemm2_kernel<<<NBUCK, 256, 0, stream>>>(rec, Bbase, hB, QwB, Qb, WwB, Wb, out);
}